// Round 1
// baseline (589.235 us; speedup 1.0000x reference)
//
#include <hip/hip_runtime.h>
#include <hip/hip_bf16.h>
#include <math.h>

#define TT 4
#define CC 512
#define HH 192
#define WW 192
#define HWSZ (HH * WW)

// ---------------------------------------------------------------------------
// Kernel 1: global average pool. One block per channel.
// ---------------------------------------------------------------------------
__global__ __launch_bounds__(256) void gap_kernel(const float* __restrict__ F,
                                                  float* __restrict__ g) {
    const int c = blockIdx.x;
    const float4* p = (const float4*)(F + (size_t)c * HWSZ);
    float s = 0.f;
    const int n4 = HWSZ / 4;  // 9216
    for (int i = threadIdx.x; i < n4; i += 256) {
        float4 v = p[i];
        s += (v.x + v.y) + (v.z + v.w);
    }
    // wave64 shuffle reduce
    #pragma unroll
    for (int off = 32; off; off >>= 1) s += __shfl_down(s, off);
    __shared__ float red[4];
    const int wave = threadIdx.x >> 6;
    const int lane = threadIdx.x & 63;
    if (lane == 0) red[wave] = s;
    __syncthreads();
    if (threadIdx.x == 0) {
        g[c] = (red[0] + red[1] + red[2] + red[3]) * (1.0f / HWSZ);
    }
}

// ---------------------------------------------------------------------------
// Kernel 2: head — B = tanh(g @ w1.T + b1); build theta; write out tails.
// 1 block, 512 threads = 8 waves; wave j computes output j.
// ---------------------------------------------------------------------------
__global__ __launch_bounds__(512) void head_kernel(const float* __restrict__ g,
                                                   const float* __restrict__ w1,
                                                   const float* __restrict__ b1,
                                                   const float* __restrict__ a,
                                                   float* __restrict__ theta,
                                                   float* __restrict__ out_tail) {
    const int wave = threadIdx.x >> 6;  // 0..7 -> which of 2*T outputs
    const int lane = threadIdx.x & 63;
    float s = 0.f;
    for (int c = lane; c < CC; c += 64) s += g[c] * w1[wave * CC + c];
    #pragma unroll
    for (int off = 32; off; off >>= 1) s += __shfl_down(s, off);
    __shared__ float B[2 * TT];
    if (lane == 0) B[wave] = tanhf(s + b1[wave]);
    __syncthreads();
    if (threadIdx.x < 2 * TT) {
        const int t = threadIdx.x >> 1;  // 0..3
        const int r = threadIdx.x & 1;   // row 0/1
        // theta (T,2,3): [a[r,0], a[r,1], B[t*2+r]]
        theta[(t * 2 + r) * 3 + 0] = a[r * 2 + 0];
        theta[(t * 2 + r) * 3 + 1] = a[r * 2 + 1];
        theta[(t * 2 + r) * 3 + 2] = B[threadIdx.x];
        // out tails: a_exp (T,2,2) flat, then B (T,2,1) flat
        out_tail[t * 4 + r * 2 + 0] = a[r * 2 + 0];
        out_tail[t * 4 + r * 2 + 1] = a[r * 2 + 1];
        out_tail[2 * TT * 2 + threadIdx.x] = B[threadIdx.x];
    }
}

// ---------------------------------------------------------------------------
// Kernel 3: bilinear grid_sample with affine grid. One thread = 4 consecutive
// w positions (float4 store). Replicates reference fp32 arithmetic exactly.
// ---------------------------------------------------------------------------
__global__ __launch_bounds__(256) void sample_kernel(const float* __restrict__ F,
                                                     const float* __restrict__ theta,
                                                     float* __restrict__ out) {
    const long i4 = (long)blockIdx.x * 256 + threadIdx.x;
    const long elem = i4 * 4;
    const int w = (int)(elem % WW);
    const long r1 = elem / WW;
    const int h = (int)(r1 % HH);
    const long r2 = r1 / HH;
    const int c = (int)(r2 % CC);
    const int t = (int)(r2 / CC);

    const float* th = theta + t * 6;
    const float t00 = th[0], t01 = th[1], t02 = th[2];
    const float t10 = th[3], t11 = th[4], t12 = th[5];

    const float ys = (h + 0.5f) * (2.0f / HH) - 1.0f;
    const float* Fc = F + (size_t)c * HWSZ;

    float res[4];
    #pragma unroll
    for (int k = 0; k < 4; ++k) {
        const float xs = (w + k + 0.5f) * (2.0f / WW) - 1.0f;
        const float gx = t00 * xs + t01 * ys + t02;
        const float gy = t10 * xs + t11 * ys + t12;
        const float ix = ((gx + 1.0f) * WW - 1.0f) * 0.5f;
        const float iy = ((gy + 1.0f) * HH - 1.0f) * 0.5f;
        const float x0f = floorf(ix);
        const float y0f = floorf(iy);
        const float fx = ix - x0f;
        const float fy = iy - y0f;
        const int x0 = (int)x0f, y0 = (int)y0f;
        const int x1 = x0 + 1, y1 = y0 + 1;
        const bool vx0 = (x0 >= 0) & (x0 < WW);
        const bool vx1 = (x1 >= 0) & (x1 < WW);
        const bool vy0 = (y0 >= 0) & (y0 < HH);
        const bool vy1 = (y1 >= 0) & (y1 < HH);
        const float v00 = (vx0 & vy0) ? Fc[y0 * WW + x0] : 0.f;
        const float v01 = (vx1 & vy0) ? Fc[y0 * WW + x1] : 0.f;
        const float v10 = (vx0 & vy1) ? Fc[y1 * WW + x0] : 0.f;
        const float v11 = (vx1 & vy1) ? Fc[y1 * WW + x1] : 0.f;
        res[k] = v00 * (1.f - fy) * (1.f - fx) + v01 * (1.f - fy) * fx
               + v10 * fy * (1.f - fx) + v11 * fy * fx;
    }
    float4 o;
    o.x = res[0]; o.y = res[1]; o.z = res[2]; o.w = res[3];
    ((float4*)out)[i4] = o;
}

// ---------------------------------------------------------------------------
extern "C" void kernel_launch(void* const* d_in, const int* in_sizes, int n_in,
                              void* d_out, int out_size, void* d_ws, size_t ws_size,
                              hipStream_t stream) {
    const float* F  = (const float*)d_in[0];
    const float* w1 = (const float*)d_in[1];
    const float* b1 = (const float*)d_in[2];
    const float* a  = (const float*)d_in[3];
    float* out = (float*)d_out;

    float* g     = (float*)d_ws;           // 512 floats
    float* theta = g + CC;                  // 24 floats

    const long trans_elems = (long)TT * CC * HH * WW;  // 75,497,472
    float* out_tail = out + trans_elems;

    gap_kernel<<<CC, 256, 0, stream>>>(F, g);
    head_kernel<<<1, 512, 0, stream>>>(g, w1, b1, a, theta, out_tail);

    const long n4 = trans_elems / 4;        // 18,874,368
    const int blocks = (int)(n4 / 256);     // 73,728
    sample_kernel<<<blocks, 256, 0, stream>>>(F, theta, out);
}

// Round 4
// 490.347 us; speedup vs baseline: 1.2017x; 1.2017x over previous
//
#include <hip/hip_runtime.h>
#include <hip/hip_bf16.h>
#include <math.h>

#define TT 4
#define CC 512
#define HH 192
#define WW 192
#define HWSZ (HH * WW)

// ---------------------------------------------------------------------------
// Kernel 1: global average pool partials. 2 blocks per channel.
// ---------------------------------------------------------------------------
__global__ __launch_bounds__(256) void gap_kernel(const float* __restrict__ F,
                                                  float* __restrict__ g_part) {
    const int c = blockIdx.x >> 1;
    const int p = blockIdx.x & 1;
    const float4* base = (const float4*)(F + (size_t)c * HWSZ);
    const int chunk = HWSZ / 8;          // 4608 float4 per partial
    const int start = p * chunk;
    float s = 0.f;
    for (int i = threadIdx.x; i < chunk; i += 256) {
        float4 v = base[start + i];
        s += (v.x + v.y) + (v.z + v.w);
    }
    #pragma unroll
    for (int off = 32; off; off >>= 1) s += __shfl_down(s, off);
    __shared__ float red[4];
    const int wave = threadIdx.x >> 6;
    const int lane = threadIdx.x & 63;
    if (lane == 0) red[wave] = s;
    __syncthreads();
    if (threadIdx.x == 0) g_part[c * 2 + p] = (red[0] + red[1]) + (red[2] + red[3]);
}

// ---------------------------------------------------------------------------
// Kernel 2: head — B = tanh(g @ w1.T + b1); build theta; write out tails.
// ---------------------------------------------------------------------------
__global__ __launch_bounds__(512) void head_kernel(const float* __restrict__ g_part,
                                                   const float* __restrict__ w1,
                                                   const float* __restrict__ b1,
                                                   const float* __restrict__ a,
                                                   float* __restrict__ theta,
                                                   float* __restrict__ out_tail) {
    const int wave = threadIdx.x >> 6;  // 0..7 -> which of 2*T outputs
    const int lane = threadIdx.x & 63;
    float s = 0.f;
    for (int c = lane; c < CC; c += 64) {
        const float gc = (g_part[2 * c] + g_part[2 * c + 1]) * (1.0f / HWSZ);
        s += gc * w1[wave * CC + c];
    }
    #pragma unroll
    for (int off = 32; off; off >>= 1) s += __shfl_down(s, off);
    __shared__ float B[2 * TT];
    if (lane == 0) B[wave] = tanhf(s + b1[wave]);
    __syncthreads();
    if (threadIdx.x < 2 * TT) {
        const int t = threadIdx.x >> 1;  // 0..3
        const int r = threadIdx.x & 1;   // row 0/1
        theta[(t * 2 + r) * 3 + 0] = a[r * 2 + 0];
        theta[(t * 2 + r) * 3 + 1] = a[r * 2 + 1];
        theta[(t * 2 + r) * 3 + 2] = B[threadIdx.x];
        out_tail[t * 4 + r * 2 + 0] = a[r * 2 + 0];
        out_tail[t * 4 + r * 2 + 1] = a[r * 2 + 1];
        out_tail[2 * TT * 2 + threadIdx.x] = B[threadIdx.x];
    }
}

// ---------------------------------------------------------------------------
// Kernel 3: bilinear grid_sample. Fast path for identity linear part
// (pure translation -> per-t constant weights, shifted 2x2 blend).
// General affine fallback kept for correctness (branch is wave-uniform:
// t and c are constant within a block).
// ---------------------------------------------------------------------------
__global__ __launch_bounds__(256) void sample_kernel(const float* __restrict__ F,
                                                     const float* __restrict__ theta,
                                                     float* __restrict__ out) {
    const long i4 = (long)blockIdx.x * 256 + threadIdx.x;
    const long elem = i4 * 4;
    const int w = (int)(elem % WW);
    const long r1 = elem / WW;
    const int h = (int)(r1 % HH);
    const long r2 = r1 / HH;
    const int c = (int)(r2 % CC);
    const int t = (int)(r2 / CC);

    const float* th = theta + t * 6;
    const float t00 = th[0], t01 = th[1], t02 = th[2];
    const float t10 = th[3], t11 = th[4], t12 = th[5];
    const float* Fc = F + (size_t)c * HWSZ;

    float res[4];

    if (t00 == 1.f && t01 == 0.f && t10 == 0.f && t11 == 1.f) {
        // -------- pure translation fast path --------
        // ix = w + t02*W/2, iy = h + t12*H/2 (constant shift + frac per t)
        const float sxf = t02 * (0.5f * WW);
        const float syf = t12 * (0.5f * HH);
        const float oxf = floorf(sxf);
        const float oyf = floorf(syf);
        const float fx = sxf - oxf;
        const float fy = syf - oyf;
        const int x0 = w + (int)oxf;
        const int y0 = h + (int)oyf;
        const int y1 = y0 + 1;
        const bool vy0 = ((unsigned)y0 < (unsigned)HH);
        const bool vy1 = ((unsigned)y1 < (unsigned)HH);
        const float* r0 = Fc + y0 * WW;
        const float* r1p = Fc + y1 * WW;
        float a0[5], a1[5];
        #pragma unroll
        for (int j = 0; j < 5; ++j) {
            const int xj = x0 + j;
            const bool vx = ((unsigned)xj < (unsigned)WW);
            a0[j] = (vx & vy0) ? r0[xj] : 0.f;
            a1[j] = (vx & vy1) ? r1p[xj] : 0.f;
        }
        #pragma unroll
        for (int k = 0; k < 4; ++k) {
            const float top = a0[k] + fx * (a0[k + 1] - a0[k]);
            const float bot = a1[k] + fx * (a1[k + 1] - a1[k]);
            res[k] = top + fy * (bot - top);
        }
    } else {
        // -------- general affine fallback --------
        const float ys = (h + 0.5f) * (2.0f / HH) - 1.0f;
        #pragma unroll
        for (int k = 0; k < 4; ++k) {
            const float xs = (w + k + 0.5f) * (2.0f / WW) - 1.0f;
            const float gx = t00 * xs + t01 * ys + t02;
            const float gy = t10 * xs + t11 * ys + t12;
            const float ix = ((gx + 1.0f) * WW - 1.0f) * 0.5f;
            const float iy = ((gy + 1.0f) * HH - 1.0f) * 0.5f;
            const float x0f = floorf(ix);
            const float y0f = floorf(iy);
            const float fx = ix - x0f;
            const float fy = iy - y0f;
            const int x0 = (int)x0f, y0 = (int)y0f;
            const int x1 = x0 + 1, y1 = y0 + 1;
            const bool vx0 = (x0 >= 0) & (x0 < WW);
            const bool vx1 = (x1 >= 0) & (x1 < WW);
            const bool vy0 = (y0 >= 0) & (y0 < HH);
            const bool vy1 = (y1 >= 0) & (y1 < HH);
            const float v00 = (vx0 & vy0) ? Fc[y0 * WW + x0] : 0.f;
            const float v01 = (vx1 & vy0) ? Fc[y0 * WW + x1] : 0.f;
            const float v10 = (vx0 & vy1) ? Fc[y1 * WW + x0] : 0.f;
            const float v11 = (vx1 & vy1) ? Fc[y1 * WW + x1] : 0.f;
            res[k] = v00 * (1.f - fy) * (1.f - fx) + v01 * (1.f - fy) * fx
                   + v10 * fy * (1.f - fx) + v11 * fy * fx;
        }
    }

    float4 o;
    o.x = res[0]; o.y = res[1]; o.z = res[2]; o.w = res[3];
    ((float4*)out)[i4] = o;
}

// ---------------------------------------------------------------------------
extern "C" void kernel_launch(void* const* d_in, const int* in_sizes, int n_in,
                              void* d_out, int out_size, void* d_ws, size_t ws_size,
                              hipStream_t stream) {
    const float* F  = (const float*)d_in[0];
    const float* w1 = (const float*)d_in[1];
    const float* b1 = (const float*)d_in[2];
    const float* a  = (const float*)d_in[3];
    float* out = (float*)d_out;

    float* g_part = (float*)d_ws;            // 1024 floats
    float* theta  = g_part + 2 * CC;         // 24 floats

    const long trans_elems = (long)TT * CC * HH * WW;  // 75,497,472
    float* out_tail = out + trans_elems;

    gap_kernel<<<2 * CC, 256, 0, stream>>>(F, g_part);
    head_kernel<<<1, 512, 0, stream>>>(g_part, w1, b1, a, theta, out_tail);

    const long n4 = trans_elems / 4;         // 18,874,368
    const int blocks = (int)(n4 / 256);      // 73,728
    sample_kernel<<<blocks, 256, 0, stream>>>(F, theta, out);
}

// Round 6
// 401.683 us; speedup vs baseline: 1.4669x; 1.2207x over previous
//
#include <hip/hip_runtime.h>
#include <hip/hip_bf16.h>
#include <math.h>

#define TT 4
#define CC 512
#define HH 192
#define WW 192
#define HWSZ (HH * WW)
#define W4N 48               // float4s per row
#define PLANE4 (HH * W4N)    // 9216 float4 slots per plane

typedef float vfloat4 __attribute__((ext_vector_type(4)));  // clang-native, ok for nontemporal builtins

// ---------------------------------------------------------------------------
// Kernel 1: global average pool partials. 2 blocks per channel.
// ---------------------------------------------------------------------------
__global__ __launch_bounds__(256) void gap_kernel(const float* __restrict__ F,
                                                  float* __restrict__ g_part) {
    const int c = blockIdx.x >> 1;
    const int p = blockIdx.x & 1;
    const float4* base = (const float4*)(F + (size_t)c * HWSZ);
    const int chunk = HWSZ / 8;          // 4608 float4 per partial
    const int start = p * chunk;
    float s = 0.f;
    for (int i = threadIdx.x; i < chunk; i += 256) {
        float4 v = base[start + i];
        s += (v.x + v.y) + (v.z + v.w);
    }
    #pragma unroll
    for (int off = 32; off; off >>= 1) s += __shfl_down(s, off);
    __shared__ float red[4];
    const int wave = threadIdx.x >> 6;
    const int lane = threadIdx.x & 63;
    if (lane == 0) red[wave] = s;
    __syncthreads();
    if (threadIdx.x == 0) g_part[c * 2 + p] = (red[0] + red[1]) + (red[2] + red[3]);
}

// ---------------------------------------------------------------------------
// Kernel 2: head — B = tanh(g @ w1.T + b1); theta; per-t sample params; tails.
// ---------------------------------------------------------------------------
__global__ __launch_bounds__(512) void head_kernel(const float* __restrict__ g_part,
                                                   const float* __restrict__ w1,
                                                   const float* __restrict__ b1,
                                                   const float* __restrict__ a,
                                                   float* __restrict__ theta,
                                                   float* __restrict__ params,
                                                   float* __restrict__ out_tail) {
    const int wave = threadIdx.x >> 6;  // 0..7 -> which of 2*T outputs
    const int lane = threadIdx.x & 63;
    float s = 0.f;
    for (int c = lane; c < CC; c += 64) {
        const float gc = (g_part[2 * c] + g_part[2 * c + 1]) * (1.0f / HWSZ);
        s += gc * w1[wave * CC + c];
    }
    #pragma unroll
    for (int off = 32; off; off >>= 1) s += __shfl_down(s, off);
    __shared__ float B[2 * TT];
    if (lane == 0) B[wave] = tanhf(s + b1[wave]);
    __syncthreads();
    if (threadIdx.x < 2 * TT) {
        const int t = threadIdx.x >> 1;  // 0..3
        const int r = threadIdx.x & 1;   // row 0/1
        theta[(t * 2 + r) * 3 + 0] = a[r * 2 + 0];
        theta[(t * 2 + r) * 3 + 1] = a[r * 2 + 1];
        theta[(t * 2 + r) * 3 + 2] = B[threadIdx.x];
        out_tail[t * 4 + r * 2 + 0] = a[r * 2 + 0];
        out_tail[t * 4 + r * 2 + 1] = a[r * 2 + 1];
        out_tail[2 * TT * 2 + threadIdx.x] = B[threadIdx.x];
    }
    if (threadIdx.x < TT) {
        const int t = threadIdx.x;
        const bool ident = (a[0] == 1.f) & (a[1] == 0.f) & (a[2] == 0.f) & (a[3] == 1.f);
        const float sxf = B[t * 2 + 0] * (0.5f * WW);
        const float syf = B[t * 2 + 1] * (0.5f * HH);
        const float oxf = floorf(sxf);
        const float oyf = floorf(syf);
        params[t * 8 + 0] = ident ? 1.f : 0.f;
        params[t * 8 + 1] = oxf;
        params[t * 8 + 2] = oyf;
        params[t * 8 + 3] = sxf - oxf;
        params[t * 8 + 4] = syf - oyf;
    }
}

// ---------------------------------------------------------------------------
// Kernel 3: t-fused bilinear sample. Grid (36, 512): blockIdx.y = channel.
// Fast path (identity linear part): per t, the 5-wide window lives in two
// 4-aligned float4 blocks (x0 mod 4 is wave-uniform); invalid columns align
// exactly with float4 block boundaries, so block predication == zero padding.
// ---------------------------------------------------------------------------
__global__ __launch_bounds__(256) void sample_kernel(const float* __restrict__ F,
                                                     const float* __restrict__ theta,
                                                     const float* __restrict__ params,
                                                     float* __restrict__ out) {
    const int c = blockIdx.y;
    const int slot = blockIdx.x * 256 + threadIdx.x;  // 0..9215
    const int h = slot / W4N;
    const int w4 = slot - h * W4N;
    const int w0 = w4 * 4;
    const float* Fc = F + (size_t)c * HWSZ;
    float4* out4 = (float4*)out;
    vfloat4* out4nt = (vfloat4*)out;

    const bool allident = (params[0] != 0.f) & (params[8] != 0.f) &
                          (params[16] != 0.f) & (params[24] != 0.f);

    if (allident) {
        #pragma unroll
        for (int t = 0; t < TT; ++t) {
            const float oxf = params[t * 8 + 1];
            const float oyf = params[t * 8 + 2];
            const float fx  = params[t * 8 + 3];
            const float fy  = params[t * 8 + 4];
            const int oxi = (int)oxf;
            const int oyi = (int)oyf;
            const int y0 = h + oyi, y1 = y0 + 1;
            const bool vy0 = ((unsigned)y0 < (unsigned)HH);
            const bool vy1 = ((unsigned)y1 < (unsigned)HH);
            const int q  = oxi >> 2;                                   // floor div 4
            const int ms = __builtin_amdgcn_readfirstlane(oxi & 3);    // uniform
            const int fb = w4 + q;
            const bool f0 = ((unsigned)fb < (unsigned)W4N);
            const bool f1 = ((unsigned)(fb + 1) < (unsigned)W4N);
            const float4* r0 = (const float4*)(Fc + (size_t)y0 * WW);
            const float4* r1 = (const float4*)(Fc + (size_t)y1 * WW);
            const float4 z = {0.f, 0.f, 0.f, 0.f};
            float4 q00 = z, q01 = z, q10 = z, q11 = z;
            if (vy0 & f0) q00 = r0[fb];
            if (vy0 & f1) q01 = r0[fb + 1];
            if (vy1 & f0) q10 = r1[fb];
            if (vy1 & f1) q11 = r1[fb + 1];

            float a0, a1, a2, a3, a4, b0, b1, b2, b3, b4;
            if (ms == 0) {
                a0 = q00.x; a1 = q00.y; a2 = q00.z; a3 = q00.w; a4 = q01.x;
                b0 = q10.x; b1 = q10.y; b2 = q10.z; b3 = q10.w; b4 = q11.x;
            } else if (ms == 1) {
                a0 = q00.y; a1 = q00.z; a2 = q00.w; a3 = q01.x; a4 = q01.y;
                b0 = q10.y; b1 = q10.z; b2 = q10.w; b3 = q11.x; b4 = q11.y;
            } else if (ms == 2) {
                a0 = q00.z; a1 = q00.w; a2 = q01.x; a3 = q01.y; a4 = q01.z;
                b0 = q10.z; b1 = q10.w; b2 = q11.x; b3 = q11.y; b4 = q11.z;
            } else {
                a0 = q00.w; a1 = q01.x; a2 = q01.y; a3 = q01.z; a4 = q01.w;
                b0 = q10.w; b1 = q11.x; b2 = q11.y; b3 = q11.z; b4 = q11.w;
            }

            const float t0 = a0 + fx * (a1 - a0);
            const float t1 = a1 + fx * (a2 - a1);
            const float t2 = a2 + fx * (a3 - a2);
            const float t3 = a3 + fx * (a4 - a3);
            const float u0 = b0 + fx * (b1 - b0);
            const float u1 = b1 + fx * (b2 - b1);
            const float u2 = b2 + fx * (b3 - b2);
            const float u3 = b3 + fx * (b4 - b3);
            vfloat4 o;
            o.x = t0 + fy * (u0 - t0);
            o.y = t1 + fy * (u1 - t1);
            o.z = t2 + fy * (u2 - t2);
            o.w = t3 + fy * (u3 - t3);
            __builtin_nontemporal_store(o, &out4nt[(size_t)(t * CC + c) * PLANE4 + slot]);
        }
    } else {
        // -------- general affine fallback (reference-exact) --------
        const float ys = (h + 0.5f) * (2.0f / HH) - 1.0f;
        for (int t = 0; t < TT; ++t) {
            const float* th = theta + t * 6;
            const float t00 = th[0], t01 = th[1], t02 = th[2];
            const float t10 = th[3], t11 = th[4], t12 = th[5];
            float res[4];
            #pragma unroll
            for (int k = 0; k < 4; ++k) {
                const float xs = (w0 + k + 0.5f) * (2.0f / WW) - 1.0f;
                const float gx = t00 * xs + t01 * ys + t02;
                const float gy = t10 * xs + t11 * ys + t12;
                const float ix = ((gx + 1.0f) * WW - 1.0f) * 0.5f;
                const float iy = ((gy + 1.0f) * HH - 1.0f) * 0.5f;
                const float x0f = floorf(ix);
                const float y0f = floorf(iy);
                const float fx = ix - x0f;
                const float fy = iy - y0f;
                const int x0 = (int)x0f, y0 = (int)y0f;
                const int x1 = x0 + 1, y1 = y0 + 1;
                const bool vx0 = (x0 >= 0) & (x0 < WW);
                const bool vx1 = (x1 >= 0) & (x1 < WW);
                const bool vy0 = (y0 >= 0) & (y0 < HH);
                const bool vy1 = (y1 >= 0) & (y1 < HH);
                const float v00 = (vx0 & vy0) ? Fc[y0 * WW + x0] : 0.f;
                const float v01 = (vx1 & vy0) ? Fc[y0 * WW + x1] : 0.f;
                const float v10 = (vx0 & vy1) ? Fc[y1 * WW + x0] : 0.f;
                const float v11 = (vx1 & vy1) ? Fc[y1 * WW + x1] : 0.f;
                res[k] = v00 * (1.f - fy) * (1.f - fx) + v01 * (1.f - fy) * fx
                       + v10 * fy * (1.f - fx) + v11 * fy * fx;
            }
            float4 o;
            o.x = res[0]; o.y = res[1]; o.z = res[2]; o.w = res[3];
            out4[(size_t)(t * CC + c) * PLANE4 + slot] = o;
        }
    }
}

// ---------------------------------------------------------------------------
extern "C" void kernel_launch(void* const* d_in, const int* in_sizes, int n_in,
                              void* d_out, int out_size, void* d_ws, size_t ws_size,
                              hipStream_t stream) {
    const float* F  = (const float*)d_in[0];
    const float* w1 = (const float*)d_in[1];
    const float* b1 = (const float*)d_in[2];
    const float* a  = (const float*)d_in[3];
    float* out = (float*)d_out;

    float* g_part = (float*)d_ws;            // 1024 floats
    float* theta  = g_part + 2 * CC;         // 24 floats
    float* params = theta + 24;              // 32 floats

    const long trans_elems = (long)TT * CC * HH * WW;  // 75,497,472
    float* out_tail = out + trans_elems;

    gap_kernel<<<2 * CC, 256, 0, stream>>>(F, g_part);
    head_kernel<<<1, 512, 0, stream>>>(g_part, w1, b1, a, theta, params, out_tail);

    sample_kernel<<<dim3(PLANE4 / 256, CC), 256, 0, stream>>>(F, theta, params, out);
}

// Round 7
// 382.956 us; speedup vs baseline: 1.5386x; 1.0489x over previous
//
#include <hip/hip_runtime.h>
#include <hip/hip_bf16.h>
#include <math.h>

#define TT 4
#define CC 512
#define HH 192
#define WW 192
#define HWSZ (HH * WW)
#define W4N 48               // float4s per row
#define W8N 24               // float8 groups per row
#define PLANE4 (HH * W4N)    // 9216 float4 slots per plane
#define PLANE8 (HH * W8N)    // 4608 float8 slots per plane

typedef float vfloat4 __attribute__((ext_vector_type(4)));  // clang-native, ok for nontemporal builtins

// ---------------------------------------------------------------------------
// Kernel 1: global average pool partials. 2 blocks per channel.
// ---------------------------------------------------------------------------
__global__ __launch_bounds__(256) void gap_kernel(const float* __restrict__ F,
                                                  float* __restrict__ g_part) {
    const int c = blockIdx.x >> 1;
    const int p = blockIdx.x & 1;
    const float4* base = (const float4*)(F + (size_t)c * HWSZ);
    const int chunk = HWSZ / 8;          // 4608 float4 per partial
    const int start = p * chunk;
    float s = 0.f;
    for (int i = threadIdx.x; i < chunk; i += 256) {
        float4 v = base[start + i];
        s += (v.x + v.y) + (v.z + v.w);
    }
    #pragma unroll
    for (int off = 32; off; off >>= 1) s += __shfl_down(s, off);
    __shared__ float red[4];
    const int wave = threadIdx.x >> 6;
    const int lane = threadIdx.x & 63;
    if (lane == 0) red[wave] = s;
    __syncthreads();
    if (threadIdx.x == 0) g_part[c * 2 + p] = (red[0] + red[1]) + (red[2] + red[3]);
}

// ---------------------------------------------------------------------------
// Kernel 2: head — B = tanh(g @ w1.T + b1); theta; per-t sample params; tails.
// ---------------------------------------------------------------------------
__global__ __launch_bounds__(512) void head_kernel(const float* __restrict__ g_part,
                                                   const float* __restrict__ w1,
                                                   const float* __restrict__ b1,
                                                   const float* __restrict__ a,
                                                   float* __restrict__ theta,
                                                   float* __restrict__ params,
                                                   float* __restrict__ out_tail) {
    const int wave = threadIdx.x >> 6;  // 0..7 -> which of 2*T outputs
    const int lane = threadIdx.x & 63;
    float s = 0.f;
    for (int c = lane; c < CC; c += 64) {
        const float gc = (g_part[2 * c] + g_part[2 * c + 1]) * (1.0f / HWSZ);
        s += gc * w1[wave * CC + c];
    }
    #pragma unroll
    for (int off = 32; off; off >>= 1) s += __shfl_down(s, off);
    __shared__ float B[2 * TT];
    if (lane == 0) B[wave] = tanhf(s + b1[wave]);
    __syncthreads();
    if (threadIdx.x < 2 * TT) {
        const int t = threadIdx.x >> 1;  // 0..3
        const int r = threadIdx.x & 1;   // row 0/1
        theta[(t * 2 + r) * 3 + 0] = a[r * 2 + 0];
        theta[(t * 2 + r) * 3 + 1] = a[r * 2 + 1];
        theta[(t * 2 + r) * 3 + 2] = B[threadIdx.x];
        out_tail[t * 4 + r * 2 + 0] = a[r * 2 + 0];
        out_tail[t * 4 + r * 2 + 1] = a[r * 2 + 1];
        out_tail[2 * TT * 2 + threadIdx.x] = B[threadIdx.x];
    }
    if (threadIdx.x < TT) {
        const int t = threadIdx.x;
        const bool ident = (a[0] == 1.f) & (a[1] == 0.f) & (a[2] == 0.f) & (a[3] == 1.f);
        const float sxf = B[t * 2 + 0] * (0.5f * WW);
        const float syf = B[t * 2 + 1] * (0.5f * HH);
        const float oxf = floorf(sxf);
        const float oyf = floorf(syf);
        params[t * 8 + 0] = ident ? 1.f : 0.f;
        params[t * 8 + 1] = oxf;
        params[t * 8 + 2] = oyf;
        params[t * 8 + 3] = sxf - oxf;
        params[t * 8 + 4] = syf - oyf;
    }
}

// ---------------------------------------------------------------------------
// Kernel 3: t-fused bilinear sample, 8 floats per thread.
// Grid (18, 512): blockIdx.y = channel. Fast path (identity linear part):
// per t, the 9-wide window lives in three 4-aligned float4 blocks (x0 mod 4
// wave-uniform); invalid columns align exactly with float4 block boundaries,
// so block predication == zero padding.
// ---------------------------------------------------------------------------
__global__ __launch_bounds__(256) void sample_kernel(const float* __restrict__ F,
                                                     const float* __restrict__ theta,
                                                     const float* __restrict__ params,
                                                     float* __restrict__ out) {
    const int c = blockIdx.y;
    const int slot8 = blockIdx.x * 256 + threadIdx.x;  // 0..4607
    const int h = slot8 / W8N;
    const int w8 = slot8 - h * W8N;
    const int w0 = w8 * 8;
    const float* Fc = F + (size_t)c * HWSZ;
    float4* out4 = (float4*)out;
    vfloat4* out4nt = (vfloat4*)out;

    const bool allident = (params[0] != 0.f) & (params[8] != 0.f) &
                          (params[16] != 0.f) & (params[24] != 0.f);

    if (allident) {
        #pragma unroll
        for (int t = 0; t < TT; ++t) {
            const float oxf = params[t * 8 + 1];
            const float oyf = params[t * 8 + 2];
            const float fx  = params[t * 8 + 3];
            const float fy  = params[t * 8 + 4];
            const int oxi = (int)oxf;
            const int oyi = (int)oyf;
            const int y0 = h + oyi, y1 = y0 + 1;
            const bool vy0 = ((unsigned)y0 < (unsigned)HH);
            const bool vy1 = ((unsigned)y1 < (unsigned)HH);
            const int q  = oxi >> 2;                                   // floor div 4
            const int ms = __builtin_amdgcn_readfirstlane(oxi & 3);    // uniform
            const int fb = w8 * 2 + q;
            const bool f0 = ((unsigned)fb < (unsigned)W4N);
            const bool f1 = ((unsigned)(fb + 1) < (unsigned)W4N);
            const bool f2 = ((unsigned)(fb + 2) < (unsigned)W4N);
            const float4* r0 = (const float4*)(Fc + (size_t)y0 * WW);
            const float4* r1 = (const float4*)(Fc + (size_t)y1 * WW);
            const float4 z = {0.f, 0.f, 0.f, 0.f};
            float4 q00 = z, q01 = z, q02 = z, q10 = z, q11 = z, q12 = z;
            if (vy0 & f0) q00 = r0[fb];
            if (vy0 & f1) q01 = r0[fb + 1];
            if (vy0 & f2) q02 = r0[fb + 2];
            if (vy1 & f0) q10 = r1[fb];
            if (vy1 & f1) q11 = r1[fb + 1];
            if (vy1 & f2) q12 = r1[fb + 2];

            // window a[0..8] = rowwindow[ms..ms+8] from 12 floats, ms uniform
            float a[9], b[9];
            {
                const float fa[12] = {q00.x, q00.y, q00.z, q00.w,
                                      q01.x, q01.y, q01.z, q01.w,
                                      q02.x, q02.y, q02.z, q02.w};
                const float fbr[12] = {q10.x, q10.y, q10.z, q10.w,
                                       q11.x, q11.y, q11.z, q11.w,
                                       q12.x, q12.y, q12.z, q12.w};
                if (ms == 0) {
                    #pragma unroll
                    for (int i = 0; i < 9; ++i) { a[i] = fa[i];     b[i] = fbr[i]; }
                } else if (ms == 1) {
                    #pragma unroll
                    for (int i = 0; i < 9; ++i) { a[i] = fa[i + 1]; b[i] = fbr[i + 1]; }
                } else if (ms == 2) {
                    #pragma unroll
                    for (int i = 0; i < 9; ++i) { a[i] = fa[i + 2]; b[i] = fbr[i + 2]; }
                } else {
                    #pragma unroll
                    for (int i = 0; i < 9; ++i) { a[i] = fa[i + 3]; b[i] = fbr[i + 3]; }
                }
            }

            float r[8];
            #pragma unroll
            for (int k = 0; k < 8; ++k) {
                const float top = a[k] + fx * (a[k + 1] - a[k]);
                const float bot = b[k] + fx * (b[k + 1] - b[k]);
                r[k] = top + fy * (bot - top);
            }
            const size_t obase = (size_t)(t * CC + c) * PLANE4 + (size_t)h * W4N + w8 * 2;
            vfloat4 o0, o1;
            o0.x = r[0]; o0.y = r[1]; o0.z = r[2]; o0.w = r[3];
            o1.x = r[4]; o1.y = r[5]; o1.z = r[6]; o1.w = r[7];
            __builtin_nontemporal_store(o0, &out4nt[obase]);
            __builtin_nontemporal_store(o1, &out4nt[obase + 1]);
        }
    } else {
        // -------- general affine fallback (reference-exact) --------
        const float ys = (h + 0.5f) * (2.0f / HH) - 1.0f;
        for (int t = 0; t < TT; ++t) {
            const float* th = theta + t * 6;
            const float t00 = th[0], t01 = th[1], t02 = th[2];
            const float t10 = th[3], t11 = th[4], t12 = th[5];
            float res[8];
            #pragma unroll
            for (int k = 0; k < 8; ++k) {
                const float xs = (w0 + k + 0.5f) * (2.0f / WW) - 1.0f;
                const float gx = t00 * xs + t01 * ys + t02;
                const float gy = t10 * xs + t11 * ys + t12;
                const float ix = ((gx + 1.0f) * WW - 1.0f) * 0.5f;
                const float iy = ((gy + 1.0f) * HH - 1.0f) * 0.5f;
                const float x0f = floorf(ix);
                const float y0f = floorf(iy);
                const float fx = ix - x0f;
                const float fy = iy - y0f;
                const int x0 = (int)x0f, y0 = (int)y0f;
                const int x1 = x0 + 1, y1 = y0 + 1;
                const bool vx0 = (x0 >= 0) & (x0 < WW);
                const bool vx1 = (x1 >= 0) & (x1 < WW);
                const bool vy0 = (y0 >= 0) & (y0 < HH);
                const bool vy1 = (y1 >= 0) & (y1 < HH);
                const float v00 = (vx0 & vy0) ? Fc[y0 * WW + x0] : 0.f;
                const float v01 = (vx1 & vy0) ? Fc[y0 * WW + x1] : 0.f;
                const float v10 = (vx0 & vy1) ? Fc[y1 * WW + x0] : 0.f;
                const float v11 = (vx1 & vy1) ? Fc[y1 * WW + x1] : 0.f;
                res[k] = v00 * (1.f - fy) * (1.f - fx) + v01 * (1.f - fy) * fx
                       + v10 * fy * (1.f - fx) + v11 * fy * fx;
            }
            const size_t obase = (size_t)(t * CC + c) * PLANE4 + (size_t)h * W4N + w8 * 2;
            float4 o0, o1;
            o0.x = res[0]; o0.y = res[1]; o0.z = res[2]; o0.w = res[3];
            o1.x = res[4]; o1.y = res[5]; o1.z = res[6]; o1.w = res[7];
            out4[obase] = o0;
            out4[obase + 1] = o1;
        }
    }
}

// ---------------------------------------------------------------------------
extern "C" void kernel_launch(void* const* d_in, const int* in_sizes, int n_in,
                              void* d_out, int out_size, void* d_ws, size_t ws_size,
                              hipStream_t stream) {
    const float* F  = (const float*)d_in[0];
    const float* w1 = (const float*)d_in[1];
    const float* b1 = (const float*)d_in[2];
    const float* a  = (const float*)d_in[3];
    float* out = (float*)d_out;

    float* g_part = (float*)d_ws;            // 1024 floats
    float* theta  = g_part + 2 * CC;         // 24 floats
    float* params = theta + 24;              // 32 floats

    const long trans_elems = (long)TT * CC * HH * WW;  // 75,497,472
    float* out_tail = out + trans_elems;

    gap_kernel<<<2 * CC, 256, 0, stream>>>(F, g_part);
    head_kernel<<<1, 512, 0, stream>>>(g_part, w1, b1, a, theta, params, out_tail);

    sample_kernel<<<dim3(PLANE8 / 256, CC), 256, 0, stream>>>(F, theta, params, out);
}